// Round 5
// baseline (174.875 us; speedup 1.0000x reference)
//
#include <hip/hip_runtime.h>
#include <math.h>

#define TSEQ 2048
#define NB 4
#define DM 512
#define NH 8
#define HD 64

typedef _Float16 half8 __attribute__((ext_vector_type(8)));
typedef _Float16 half4 __attribute__((ext_vector_type(4)));
typedef float floatx4 __attribute__((ext_vector_type(4)));

// ---------------- zero-init workspace (restores validation-time initial state) ----
__global__ void zero_ws(float4* __restrict__ p, int n16) {
  const float4 z = make_float4(0.f, 0.f, 0.f, 0.f);
  for (int i = blockIdx.x * blockDim.x + threadIdx.x; i < n16; i += gridDim.x * blockDim.x)
    p[i] = z;
}

// ---------------- merged f32 -> f16 conversion prepass (x, Wqkv, out_w) ----------
__global__ void cvt_all(const float* __restrict__ x, const float* __restrict__ wqkv,
                        const float* __restrict__ ow, _Float16* __restrict__ xh,
                        _Float16* __restrict__ wqkvh, _Float16* __restrict__ owh) {
  const int i = blockIdx.x * 256 + threadIdx.x;   // half8 groups: 524288 + 98304 + 32768
  const float* s; _Float16* d; int o;
  if (i < 524288)      { s = x;    d = xh;    o = i; }
  else if (i < 622592) { s = wqkv; d = wqkvh; o = i - 524288; }
  else                 { s = ow;   d = owh;   o = i - 622592; }
  const float4 a = ((const float4*)s)[2 * o];
  const float4 b = ((const float4*)s)[2 * o + 1];
  half8 h;
  h[0] = (_Float16)a.x; h[1] = (_Float16)a.y; h[2] = (_Float16)a.z; h[3] = (_Float16)a.w;
  h[4] = (_Float16)b.x; h[5] = (_Float16)b.y; h[6] = (_Float16)b.z; h[7] = (_Float16)b.w;
  *(half8*)&d[(size_t)o * 8] = h;
}

// ---------------- RoPE cos/sin table: [t][i] -> (cos, sin) ----------------
__global__ void rope_tab(float2* __restrict__ tab) {
  const int id = blockIdx.x * 256 + threadIdx.x;   // 0..65535
  const int t = id >> 5, i = id & 31;
  const float invf = powf(10000.0f, -(float)(2 * i) * (1.0f / 64.0f));
  float s, c;
  sincosf((float)t * invf, &s, &c);
  tab[id] = make_float2(c, s);
}

// ---------------- QKV GEMM (f16 MFMA) + fused RoPE ----------------
__global__ __launch_bounds__(256) void qkv_gemm_mfma(
    const _Float16* __restrict__ A, const _Float16* __restrict__ B,
    const float2* __restrict__ rope,
    _Float16* __restrict__ qb, _Float16* __restrict__ kb, _Float16* __restrict__ vT)
{
  __shared__ _Float16 As[128 * 40];
  __shared__ _Float16 Bs[128 * 40];
  const int tid = threadIdx.x;
  const int wv = tid >> 6, lane = tid & 63, quad = lane >> 4, col = lane & 15;
  const int wm = wv >> 1, we = wv & 1;
  const int m0 = blockIdx.x << 7, c0 = blockIdx.y << 7;
  const int sr = tid >> 1, sc = (tid & 1) << 4;
  const _Float16* ap = &A[(size_t)(m0 + sr) * DM + sc];
  const _Float16* bp = &B[(size_t)(c0 + sr) * DM + sc];
  floatx4 acc[4][4] = {};   // [mt][et]
  for (int k0 = 0; k0 < DM; k0 += 32) {
    const half8 a0 = *(const half8*)(ap + k0);
    const half8 a1 = *(const half8*)(ap + k0 + 8);
    const half8 b0 = *(const half8*)(bp + k0);
    const half8 b1 = *(const half8*)(bp + k0 + 8);
    __syncthreads();
    *(half8*)&As[sr * 40 + sc] = a0;
    *(half8*)&As[sr * 40 + sc + 8] = a1;
    *(half8*)&Bs[sr * 40 + sc] = b0;
    *(half8*)&Bs[sr * 40 + sc + 8] = b1;
    __syncthreads();
    half8 af[4], bf[4];
#pragma unroll
    for (int mt = 0; mt < 4; mt++)
      af[mt] = *(const half8*)&As[(wm * 64 + mt * 16 + col) * 40 + quad * 8];
#pragma unroll
    for (int et = 0; et < 4; et++)
      bf[et] = *(const half8*)&Bs[(we * 64 + et * 16 + col) * 40 + quad * 8];
#pragma unroll
    for (int mt = 0; mt < 4; mt++)
#pragma unroll
      for (int et = 0; et < 4; et++)
        acc[mt][et] = __builtin_amdgcn_mfma_f32_16x16x32_f16(af[mt], bf[et], acc[mt][et], 0, 0, 0);
  }
  const int eidx = (c0 >> 6) + we;            // 0..23, wave-uniform
  const int three = eidx >> 3, h = eidx & 7;
  const int mbase = m0 + wm * 64 + quad * 4;
  if (three == 2) {
#pragma unroll
    for (int mt = 0; mt < 4; mt++) {
      const int m = mbase + mt * 16;
      const int n = m >> 11, t = m & 2047;
#pragma unroll
      for (int et = 0; et < 4; et++) {
        const int dh = et * 16 + col;
        half4 hv;
#pragma unroll
        for (int r = 0; r < 4; r++) hv[r] = (_Float16)acc[mt][et][r];
        *(half4*)&vT[(size_t)(n * NH + h) * HD * TSEQ + (size_t)dh * TSEQ + t] = hv;
      }
    }
  } else {
    _Float16* dst = three ? kb : qb;
    const float scl = three ? 1.0f : 0.125f;
#pragma unroll
    for (int mt = 0; mt < 4; mt++)
#pragma unroll
      for (int r = 0; r < 4; r++) {
        const int m = mbase + mt * 16 + r;
        const int n = m >> 11, t = m & 2047;
#pragma unroll
        for (int et = 0; et < 4; et++) {
          const int i = ((et & 1) << 4) + col;
          const float2 cs = rope[t * 32 + i];
          const float v = acc[mt][et][r];
          const float v2 = acc[mt][et ^ 2][r];
          const float o = (et < 2) ? (v * cs.x - v2 * cs.y) : (v * cs.x + v2 * cs.y);
          dst[((size_t)(n * NH + h) * TSEQ + t) * HD + et * 16 + col] = (_Float16)(o * scl);
        }
      }
  }
}

// ---------------- windowed attention, flat (no online softmax, no barriers) ------
// One WAVE per 16 queries x head. Window <= 256 keys -> full score strip in regs.
// S^T via MFMA (A=K direct from global, B=Q^T direct from global); single softmax;
// P^T -> wave-private LDS -> A-frags; PV with V^T B-frags direct from global.
__global__ __launch_bounds__(256) void attn_flat(
    const _Float16* __restrict__ qb, const _Float16* __restrict__ kb,
    const _Float16* __restrict__ vT, _Float16* __restrict__ ctx)
{
  __shared__ __align__(16) _Float16 smem[4 * 16 * 296];   // 37,888 B, per-wave slices
  const int tid = threadIdx.x;
  const int wv = tid >> 6, lane = tid & 63, quad = lane >> 4, col = lane & 15;
  const int nh = blockIdx.y;
  const int strip = blockIdx.x * 4 + wv;      // 0..127
  const int i0 = strip << 4;
  const _Float16* qp = qb + (size_t)nh * TSEQ * HD;
  const _Float16* kp = kb + (size_t)nh * TSEQ * HD;
  const _Float16* vp = vT + (size_t)nh * HD * TSEQ;
  _Float16* Ps = smem + wv * 16 * 296;

  // Q B-frags (q pre-scaled by 1/8): B[k=d][n=i], n=col -> i=i0+col, k=quad*8+e
  const half8 qf0 = *(const half8*)&qp[(size_t)(i0 + col) * HD + (quad << 3)];
  const half8 qf1 = *(const half8*)&qp[(size_t)(i0 + col) * HD + 32 + (quad << 3)];

  const int jt0 = (i0 >> 4) - 8;              // first 16-wide j-tile (may be < 0)
  const int jbase = jt0 << 4;
  floatx4 S[18];
#pragma unroll
  for (int t = 0; t < 18; t++) { S[t][0] = -INFINITY; S[t][1] = -INFINITY; S[t][2] = -INFINITY; S[t][3] = -INFINITY; }
#pragma unroll
  for (int t = 0; t < 18; t++) {
    const int jt = jt0 + t;
    if (jt < 0 || jt >= 128) continue;        // wave-uniform skip; S stays -inf
    const int j = (jt << 4) + col;            // A[m=j_local][k=d], m=col
    const half8 a0 = *(const half8*)&kp[(size_t)j * HD + (quad << 3)];
    const half8 a1 = *(const half8*)&kp[(size_t)j * HD + 32 + (quad << 3)];
    floatx4 c = {0.f, 0.f, 0.f, 0.f};
    c = __builtin_amdgcn_mfma_f32_16x16x32_f16(a0, qf0, c, 0, 0, 0);
    c = __builtin_amdgcn_mfma_f32_16x16x32_f16(a1, qf1, c, 0, 0, 0);
    S[t] = c;
  }
  // window mask + max (lane's query: i = i0+col; lane's j: jbase + t*16 + quad*4 + r)
  const int ig = i0 + col;
  float mx = -INFINITY;
#pragma unroll
  for (int t = 0; t < 18; t++)
#pragma unroll
    for (int r = 0; r < 4; r++) {
      const int jg = jbase + (t << 4) + (quad << 2) + r;
      const bool valid = (jg >= ig - 127) && (jg <= ig + 128);
      const float s = valid ? S[t][r] : -INFINITY;
      S[t][r] = s;
      mx = fmaxf(mx, s);
    }
  mx = fmaxf(mx, __shfl_xor(mx, 16, 64));
  mx = fmaxf(mx, __shfl_xor(mx, 32, 64));
  float lsum = 0.f;
#pragma unroll
  for (int t = 0; t < 18; t++) {
    half4 ph;
#pragma unroll
    for (int r = 0; r < 4; r++) {
      const float p = __expf(S[t][r] - mx);   // exp(-inf) = 0 covers all masking
      lsum += p;
      ph[r] = (_Float16)p;
    }
    *(half4*)&Ps[col * 296 + (t << 4) + (quad << 2)] = ph;
  }
  lsum += __shfl_xor(lsum, 16, 64);
  lsum += __shfl_xor(lsum, 32, 64);
  const float linv = 1.0f / lsum;

  // PV: A = P[i][j-chunk] from wave-private LDS, B = V^T direct from global
  floatx4 accO[4] = {};
#pragma unroll
  for (int c = 0; c < 9; c++) {
    const int jlo = jbase + (c << 5);
    if (jlo + 31 < 0 || jlo > TSEQ - 1) continue;   // fully OOB chunk: P == 0
    const half8 pa = *(const half8*)&Ps[col * 296 + (c << 5) + (quad << 3)];
    int jb = jlo + (quad << 3);                     // multiple of 8
    jb = jb < 0 ? 0 : (jb > TSEQ - 8 ? TSEQ - 8 : jb);  // clamp: P=0 there anyway
#pragma unroll
    for (int d4 = 0; d4 < 4; d4++) {
      const half8 vbf = *(const half8*)&vp[(size_t)((d4 << 4) + col) * TSEQ + jb];
      accO[d4] = __builtin_amdgcn_mfma_f32_16x16x32_f16(pa, vbf, accO[d4], 0, 0, 0);
    }
  }
  // normalize + output via wave-private LDS transpose (stride 72), no barrier needed
  _Float16* Osh = Ps;
  float lr[4];
#pragma unroll
  for (int r = 0; r < 4; r++) lr[r] = __shfl(linv, (quad << 2) + r, 64);
#pragma unroll
  for (int d4 = 0; d4 < 4; d4++)
#pragma unroll
    for (int r = 0; r < 4; r++)
      Osh[((quad << 2) + r) * 72 + (d4 << 4) + col] = (_Float16)(accO[d4][r] * lr[r]);
  {
    const int n = nh >> 3, h = nh & 7;
    const int row = lane >> 2, cc = lane & 3;
    _Float16* dst = &ctx[((size_t)n * TSEQ + i0 + row) * DM + h * HD + (cc << 4)];
    *(half8*)dst = *(const half8*)&Osh[row * 72 + (cc << 4)];
    *(half8*)(dst + 8) = *(const half8*)&Osh[row * 72 + (cc << 4) + 8];
  }
}

// ---------------- output projection (f16 MFMA) + bias, f32 out ----------------
__global__ __launch_bounds__(256) void out_gemm_mfma(
    const _Float16* __restrict__ A, const _Float16* __restrict__ B,
    const float* __restrict__ bias, float* __restrict__ out)
{
  __shared__ _Float16 As[128 * 40];
  __shared__ _Float16 Bs[128 * 40];
  const int tid = threadIdx.x;
  const int wv = tid >> 6, lane = tid & 63, quad = lane >> 4, col = lane & 15;
  const int wm = wv >> 1, we = wv & 1;
  const int m0 = blockIdx.x << 7, c0 = blockIdx.y << 7;
  const int sr = tid >> 1, sc = (tid & 1) << 4;
  const _Float16* ap = &A[(size_t)(m0 + sr) * DM + sc];
  const _Float16* bp = &B[(size_t)(c0 + sr) * DM + sc];
  floatx4 acc[4][4] = {};
  for (int k0 = 0; k0 < DM; k0 += 32) {
    const half8 a0 = *(const half8*)(ap + k0);
    const half8 a1 = *(const half8*)(ap + k0 + 8);
    const half8 b0 = *(const half8*)(bp + k0);
    const half8 b1 = *(const half8*)(bp + k0 + 8);
    __syncthreads();
    *(half8*)&As[sr * 40 + sc] = a0;
    *(half8*)&As[sr * 40 + sc + 8] = a1;
    *(half8*)&Bs[sr * 40 + sc] = b0;
    *(half8*)&Bs[sr * 40 + sc + 8] = b1;
    __syncthreads();
    half8 af[4], bf[4];
#pragma unroll
    for (int mt = 0; mt < 4; mt++)
      af[mt] = *(const half8*)&As[(wm * 64 + mt * 16 + col) * 40 + quad * 8];
#pragma unroll
    for (int et = 0; et < 4; et++)
      bf[et] = *(const half8*)&Bs[(we * 64 + et * 16 + col) * 40 + quad * 8];
#pragma unroll
    for (int mt = 0; mt < 4; mt++)
#pragma unroll
      for (int et = 0; et < 4; et++)
        acc[mt][et] = __builtin_amdgcn_mfma_f32_16x16x32_f16(af[mt], bf[et], acc[mt][et], 0, 0, 0);
  }
  float bb[4];
#pragma unroll
  for (int et = 0; et < 4; et++) bb[et] = bias[c0 + we * 64 + et * 16 + col];
  const int mbase = m0 + wm * 64 + quad * 4;
#pragma unroll
  for (int mt = 0; mt < 4; mt++)
#pragma unroll
    for (int r = 0; r < 4; r++) {
      const int m = mbase + mt * 16 + r;
#pragma unroll
      for (int et = 0; et < 4; et++)
        out[(size_t)m * DM + c0 + we * 64 + et * 16 + col] = acc[mt][et][r] + bb[et];
    }
}

extern "C" void kernel_launch(void* const* d_in, const int* in_sizes, int n_in,
                              void* d_out, int out_size, void* d_ws, size_t ws_size,
                              hipStream_t stream) {
  const float* x    = (const float*)d_in[0];
  const float* wqkv = (const float*)d_in[1];
  const float* ow   = (const float*)d_in[2];
  const float* ob   = (const float*)d_in[3];
  char* ws = (char*)d_ws;
  // guard-gapped layout (total 46.7 MB)
  _Float16* xh    = (_Float16*)(ws);               //  8,388,608 B
  _Float16* wqkvh = (_Float16*)(ws + 8650752);     //  1,572,864 B
  _Float16* owh   = (_Float16*)(ws + 10485760);    //    524,288 B
  _Float16* qbuf  = (_Float16*)(ws + 11534336);    //  8,388,608 B
  _Float16* kbuf  = (_Float16*)(ws + 20971520);    //  8,388,608 B
  _Float16* vTb   = (_Float16*)(ws + 29360128);    //  8,388,608 B
  _Float16* ctxh  = (_Float16*)(ws + 37748736);    //  8,388,608 B
  float2*   rope  = (float2*)  (ws + 46137344);    //    524,288 B -> end 46,661,632

  zero_ws<<<2048, 256, 0, stream>>>((float4*)ws, 46661632 / 16);
  cvt_all<<<2560, 256, 0, stream>>>(x, wqkv, ow, xh, wqkvh, owh);
  rope_tab<<<256, 256, 0, stream>>>(rope);
  qkv_gemm_mfma<<<dim3(64, 12), 256, 0, stream>>>(xh, wqkvh, rope, qbuf, kbuf, vTb);
  attn_flat<<<dim3(32, 32), 256, 0, stream>>>(qbuf, kbuf, vTb, ctxh);
  out_gemm_mfma<<<dim3(64, 4), 256, 0, stream>>>(ctxh, owh, ob, (float*)d_out);
}

// Round 6
// 139.182 us; speedup vs baseline: 1.2564x; 1.2564x over previous
//
#include <hip/hip_runtime.h>
#include <math.h>

#define TSEQ 2048
#define NB 4
#define DM 512
#define NH 8
#define HD 64

typedef _Float16 half8 __attribute__((ext_vector_type(8)));
typedef _Float16 half4 __attribute__((ext_vector_type(4)));
typedef float floatx4 __attribute__((ext_vector_type(4)));

// ws layout (bytes):
//   [0,         8388608)  xh      (f16 x)            <- cvt
//   [8650752,  10223616)  wqkvh   (f16 Wqkv)         <- cvt
//   [10485760, 11010048)  owh     (f16 out_w)        <- cvt
//   [11534336, 19922944)  qbuf
//   [20971520, 29360128)  kbuf
//   [29360128+0, ...)     vTb     at 29360128
//   [37748736, 46137344)  ctxh
//   [46137344, 46661632)  rope table (float2 [t][i])
// prep writes EVERY byte in [0, 46661632) exactly once (cvt / rope / zero).

#define WS_END_U16 2916352   // 46661632 / 16

__global__ void prep(const float* __restrict__ x, const float* __restrict__ wqkv,
                     const float* __restrict__ ow, char* __restrict__ ws) {
  for (int i = blockIdx.x * 256 + threadIdx.x; i < WS_END_U16; i += 2048 * 256) {
    if (i < 524288) {            // xh
      const float4 a = ((const float4*)x)[2 * i];
      const float4 b = ((const float4*)x)[2 * i + 1];
      half8 h;
      h[0] = (_Float16)a.x; h[1] = (_Float16)a.y; h[2] = (_Float16)a.z; h[3] = (_Float16)a.w;
      h[4] = (_Float16)b.x; h[5] = (_Float16)b.y; h[6] = (_Float16)b.z; h[7] = (_Float16)b.w;
      *(half8*)(ws + (size_t)i * 16) = h;
    } else if (i >= 540672 && i < 638976) {   // wqkvh
      const int o = i - 540672;
      const float4 a = ((const float4*)wqkv)[2 * o];
      const float4 b = ((const float4*)wqkv)[2 * o + 1];
      half8 h;
      h[0] = (_Float16)a.x; h[1] = (_Float16)a.y; h[2] = (_Float16)a.z; h[3] = (_Float16)a.w;
      h[4] = (_Float16)b.x; h[5] = (_Float16)b.y; h[6] = (_Float16)b.z; h[7] = (_Float16)b.w;
      *(half8*)(ws + (size_t)i * 16) = h;
    } else if (i >= 655360 && i < 688128) {   // owh
      const int o = i - 655360;
      const float4 a = ((const float4*)ow)[2 * o];
      const float4 b = ((const float4*)ow)[2 * o + 1];
      half8 h;
      h[0] = (_Float16)a.x; h[1] = (_Float16)a.y; h[2] = (_Float16)a.z; h[3] = (_Float16)a.w;
      h[4] = (_Float16)b.x; h[5] = (_Float16)b.y; h[6] = (_Float16)b.z; h[7] = (_Float16)b.w;
      *(half8*)(ws + (size_t)i * 16) = h;
    } else if (i >= 2883584) {                // rope table: 2 entries per 16B unit
      const int u = i - 2883584;
      float4 o4;
      {
        const int id = 2 * u, t = id >> 5, fi = id & 31;
        const float invf = powf(10000.0f, -(float)(2 * fi) * (1.0f / 64.0f));
        float s, c; sincosf((float)t * invf, &s, &c);
        o4.x = c; o4.y = s;
      }
      {
        const int id = 2 * u + 1, t = id >> 5, fi = id & 31;
        const float invf = powf(10000.0f, -(float)(2 * fi) * (1.0f / 64.0f));
        float s, c; sincosf((float)t * invf, &s, &c);
        o4.z = c; o4.w = s;
      }
      ((float4*)(ws + 46137344))[u] = o4;
    } else {                                  // gaps + q/k/v/ctx buffers -> zero
      ((float4*)ws)[i] = make_float4(0.f, 0.f, 0.f, 0.f);
    }
  }
}

// ---------------- QKV GEMM (f16 MFMA) + fused RoPE ----------------
__global__ __launch_bounds__(256) void qkv_gemm_mfma(
    const _Float16* __restrict__ A, const _Float16* __restrict__ B,
    const float2* __restrict__ rope,
    _Float16* __restrict__ qb, _Float16* __restrict__ kb, _Float16* __restrict__ vT)
{
  __shared__ _Float16 As[128 * 40];
  __shared__ _Float16 Bs[128 * 40];
  const int tid = threadIdx.x;
  const int wv = tid >> 6, lane = tid & 63, quad = lane >> 4, col = lane & 15;
  const int wm = wv >> 1, we = wv & 1;
  const int m0 = blockIdx.x << 7, c0 = blockIdx.y << 7;
  const int sr = tid >> 1, sc = (tid & 1) << 4;
  const _Float16* ap = &A[(size_t)(m0 + sr) * DM + sc];
  const _Float16* bp = &B[(size_t)(c0 + sr) * DM + sc];
  floatx4 acc[4][4] = {};   // [mt][et]
  for (int k0 = 0; k0 < DM; k0 += 32) {
    const half8 a0 = *(const half8*)(ap + k0);
    const half8 a1 = *(const half8*)(ap + k0 + 8);
    const half8 b0 = *(const half8*)(bp + k0);
    const half8 b1 = *(const half8*)(bp + k0 + 8);
    __syncthreads();
    *(half8*)&As[sr * 40 + sc] = a0;
    *(half8*)&As[sr * 40 + sc + 8] = a1;
    *(half8*)&Bs[sr * 40 + sc] = b0;
    *(half8*)&Bs[sr * 40 + sc + 8] = b1;
    __syncthreads();
    half8 af[4], bf[4];
#pragma unroll
    for (int mt = 0; mt < 4; mt++)
      af[mt] = *(const half8*)&As[(wm * 64 + mt * 16 + col) * 40 + quad * 8];
#pragma unroll
    for (int et = 0; et < 4; et++)
      bf[et] = *(const half8*)&Bs[(we * 64 + et * 16 + col) * 40 + quad * 8];
#pragma unroll
    for (int mt = 0; mt < 4; mt++)
#pragma unroll
      for (int et = 0; et < 4; et++)
        acc[mt][et] = __builtin_amdgcn_mfma_f32_16x16x32_f16(af[mt], bf[et], acc[mt][et], 0, 0, 0);
  }
  const int eidx = (c0 >> 6) + we;            // 0..23, wave-uniform
  const int three = eidx >> 3, h = eidx & 7;
  const int mbase = m0 + wm * 64 + quad * 4;
  if (three == 2) {
#pragma unroll
    for (int mt = 0; mt < 4; mt++) {
      const int m = mbase + mt * 16;
      const int n = m >> 11, t = m & 2047;
#pragma unroll
      for (int et = 0; et < 4; et++) {
        const int dh = et * 16 + col;
        half4 hv;
#pragma unroll
        for (int r = 0; r < 4; r++) hv[r] = (_Float16)acc[mt][et][r];
        *(half4*)&vT[(size_t)(n * NH + h) * HD * TSEQ + (size_t)dh * TSEQ + t] = hv;
      }
    }
  } else {
    _Float16* dst = three ? kb : qb;
    const float scl = three ? 1.0f : 0.125f;
#pragma unroll
    for (int mt = 0; mt < 4; mt++)
#pragma unroll
      for (int r = 0; r < 4; r++) {
        const int m = mbase + mt * 16 + r;
        const int n = m >> 11, t = m & 2047;
#pragma unroll
        for (int et = 0; et < 4; et++) {
          const int i = ((et & 1) << 4) + col;
          const float2 cs = rope[t * 32 + i];
          const float v = acc[mt][et][r];
          const float v2 = acc[mt][et ^ 2][r];
          const float o = (et < 2) ? (v * cs.x - v2 * cs.y) : (v * cs.x + v2 * cs.y);
          dst[((size_t)(n * NH + h) * TSEQ + t) * HD + et * 16 + col] = (_Float16)(o * scl);
        }
      }
  }
}

// ---------------- windowed flash attention (R3-proven structure) ----------------
__global__ __launch_bounds__(256, 4) void attn_win_mfma(
    const _Float16* __restrict__ qb, const _Float16* __restrict__ kb,
    const _Float16* __restrict__ vT, _Float16* __restrict__ ctx)
{
  __shared__ __align__(16) char smem[36864];
  _Float16* Ks = (_Float16*)smem;              // [64][72] j-major
  _Float16* Vt = (_Float16*)(smem + 9216);     // [64][72] d-major (from vT global)
  _Float16* Ps = (_Float16*)(smem + 18432);    // [64][72] i-major
  _Float16* Osh = (_Float16*)(smem + 27648);   // [64][72] dedicated

  const int tid = threadIdx.x;
  const int wv = tid >> 6;
  const int lane = tid & 63;
  const int quad = lane >> 4;
  const int col = lane & 15;
  const int nh = blockIdx.y;
  const int q0 = blockIdx.x << 6;
  const _Float16* qp = qb + (size_t)nh * TSEQ * HD;
  const _Float16* kp = kb + (size_t)nh * TSEQ * HD;
  const _Float16* vp = vT + (size_t)nh * HD * TSEQ;

  const int i_row = (wv << 4) + col;
  const int ig = q0 + i_row;
  const half8 qf0 = *(const half8*)&qp[(size_t)ig * HD + (quad << 3)];
  const half8 qf1 = *(const half8*)&qp[(size_t)ig * HD + 32 + (quad << 3)];

  float m_i = -1e30f, l_i = 0.0f;
  floatx4 accO[4] = {};

  const int kt0 = max(0, q0 - 127) >> 6;
  const int kt1 = min(TSEQ - 1, q0 + 191) >> 6;
  const int kr = tid >> 2, kc = (tid & 3) << 4;    // K: row j, col d
  const int vd = tid >> 2, vc = (tid & 3) << 4;    // V^T: row d, col j
  for (int kt = kt0; kt <= kt1; kt++) {
    const int j0 = kt << 6;
    const half8 k0_ = *(const half8*)&kp[(size_t)(j0 + kr) * HD + kc];
    const half8 k1_ = *(const half8*)&kp[(size_t)(j0 + kr) * HD + kc + 8];
    const half8 v0_ = *(const half8*)&vp[(size_t)vd * TSEQ + j0 + vc];
    const half8 v1_ = *(const half8*)&vp[(size_t)vd * TSEQ + j0 + vc + 8];
    __syncthreads();
    *(half8*)&Ks[kr * 72 + kc] = k0_;
    *(half8*)&Ks[kr * 72 + kc + 8] = k1_;
    *(half8*)&Vt[vd * 72 + vc] = v0_;
    *(half8*)&Vt[vd * 72 + vc + 8] = v1_;
    __syncthreads();

    floatx4 S[4];
#pragma unroll
    for (int js = 0; js < 4; js++) {
      const half8 a0 = *(const half8*)&Ks[((js << 4) + col) * 72 + (quad << 3)];
      const half8 a1 = *(const half8*)&Ks[((js << 4) + col) * 72 + 32 + (quad << 3)];
      floatx4 c = {0.f, 0.f, 0.f, 0.f};
      c = __builtin_amdgcn_mfma_f32_16x16x32_f16(a0, qf0, c, 0, 0, 0);
      c = __builtin_amdgcn_mfma_f32_16x16x32_f16(a1, qf1, c, 0, 0, 0);
      S[js] = c;
    }
    float mx = -1e30f;
#pragma unroll
    for (int js = 0; js < 4; js++)
#pragma unroll
      for (int r = 0; r < 4; r++) {
        const int jg = j0 + (js << 4) + (quad << 2) + r;
        const bool valid = (jg >= ig - 127) && (jg <= ig + 128);
        const float s = valid ? S[js][r] : -INFINITY;
        S[js][r] = s;
        mx = fmaxf(mx, s);
      }
    mx = fmaxf(mx, __shfl_xor(mx, 16, 64));
    mx = fmaxf(mx, __shfl_xor(mx, 32, 64));
    const float m_new = fmaxf(m_i, mx);
    const float alpha = __expf(m_i - m_new);
    float lsum = 0.f;
#pragma unroll
    for (int js = 0; js < 4; js++) {
      half4 ph;
#pragma unroll
      for (int r = 0; r < 4; r++) {
        const float p = __expf(S[js][r] - m_new);
        lsum += p;
        ph[r] = (_Float16)p;
      }
      *(half4*)&Ps[i_row * 72 + (js << 4) + (quad << 2)] = ph;
    }
    lsum += __shfl_xor(lsum, 16, 64);
    lsum += __shfl_xor(lsum, 32, 64);
    l_i = l_i * alpha + lsum;
    m_i = m_new;
    float a4[4];
#pragma unroll
    for (int r = 0; r < 4; r++) a4[r] = __shfl(alpha, (quad << 2) + r, 64);
#pragma unroll
    for (int d4 = 0; d4 < 4; d4++)
#pragma unroll
      for (int r = 0; r < 4; r++) accO[d4][r] *= a4[r];
    __syncthreads();
    const half8 pa0 = *(const half8*)&Ps[i_row * 72 + (quad << 3)];
    const half8 pa1 = *(const half8*)&Ps[i_row * 72 + 32 + (quad << 3)];
#pragma unroll
    for (int d4 = 0; d4 < 4; d4++) {
      const half8 vb0 = *(const half8*)&Vt[((d4 << 4) + col) * 72 + (quad << 3)];
      const half8 vb1 = *(const half8*)&Vt[((d4 << 4) + col) * 72 + 32 + (quad << 3)];
      accO[d4] = __builtin_amdgcn_mfma_f32_16x16x32_f16(pa0, vb0, accO[d4], 0, 0, 0);
      accO[d4] = __builtin_amdgcn_mfma_f32_16x16x32_f16(pa1, vb1, accO[d4], 0, 0, 0);
    }
  }
  {
    const float linv = 1.0f / l_i;
    float l4[4];
#pragma unroll
    for (int r = 0; r < 4; r++) l4[r] = __shfl(linv, (quad << 2) + r, 64);
#pragma unroll
    for (int d4 = 0; d4 < 4; d4++)
#pragma unroll
      for (int r = 0; r < 4; r++)
        Osh[((wv << 4) + (quad << 2) + r) * 72 + (d4 << 4) + col] = (_Float16)(accO[d4][r] * l4[r]);
  }
  __syncthreads();
  {
    const int n = nh >> 3, h = nh & 7;
    const int oi = tid >> 2, oc = (tid & 3) << 4;
    _Float16* dst = &ctx[((size_t)n * TSEQ + q0 + oi) * DM + h * HD + oc];
    *(half8*)&dst[0] = *(const half8*)&Osh[oi * 72 + oc];
    *(half8*)&dst[8] = *(const half8*)&Osh[oi * 72 + oc + 8];
  }
}

// ---------------- output projection (f16 MFMA) + bias, f32 out ----------------
// Tile 128x64 (grid 64x8 = 2 blocks/CU for barrier overlap). Wave tile 64x32.
__global__ __launch_bounds__(256) void out_gemm_mfma(
    const _Float16* __restrict__ A, const _Float16* __restrict__ B,
    const float* __restrict__ bias, float* __restrict__ out)
{
  __shared__ _Float16 As[128 * 40];
  __shared__ _Float16 Bs[64 * 40];
  const int tid = threadIdx.x;
  const int wv = tid >> 6, lane = tid & 63, quad = lane >> 4, col = lane & 15;
  const int wm = wv >> 1, we = wv & 1;
  const int m0 = blockIdx.x << 7, c0 = blockIdx.y << 6;
  const int sr = tid >> 1, sc = (tid & 1) << 4;     // A staging: 2 thr/row
  const int br = tid >> 2, bc = (tid & 3) << 3;     // B staging: 4 thr/row, half8 each
  const _Float16* ap = &A[(size_t)(m0 + sr) * DM + sc];
  const _Float16* bp = &B[(size_t)(c0 + br) * DM + bc];
  floatx4 acc[4][2] = {};
  for (int k0 = 0; k0 < DM; k0 += 32) {
    const half8 a0 = *(const half8*)(ap + k0);
    const half8 a1 = *(const half8*)(ap + k0 + 8);
    const half8 b0 = *(const half8*)(bp + k0);
    __syncthreads();
    *(half8*)&As[sr * 40 + sc] = a0;
    *(half8*)&As[sr * 40 + sc + 8] = a1;
    *(half8*)&Bs[br * 40 + bc] = b0;
    __syncthreads();
    half8 af[4], bf[2];
#pragma unroll
    for (int mt = 0; mt < 4; mt++)
      af[mt] = *(const half8*)&As[(wm * 64 + mt * 16 + col) * 40 + quad * 8];
#pragma unroll
    for (int et = 0; et < 2; et++)
      bf[et] = *(const half8*)&Bs[(we * 32 + et * 16 + col) * 40 + quad * 8];
#pragma unroll
    for (int mt = 0; mt < 4; mt++)
#pragma unroll
      for (int et = 0; et < 2; et++)
        acc[mt][et] = __builtin_amdgcn_mfma_f32_16x16x32_f16(af[mt], bf[et], acc[mt][et], 0, 0, 0);
  }
  float bb[2];
#pragma unroll
  for (int et = 0; et < 2; et++) bb[et] = bias[c0 + we * 32 + et * 16 + col];
  const int mbase = m0 + wm * 64 + quad * 4;
#pragma unroll
  for (int mt = 0; mt < 4; mt++)
#pragma unroll
    for (int r = 0; r < 4; r++) {
      const int m = mbase + mt * 16 + r;
#pragma unroll
      for (int et = 0; et < 2; et++)
        out[(size_t)m * DM + c0 + we * 32 + et * 16 + col] = acc[mt][et][r] + bb[et];
    }
}

extern "C" void kernel_launch(void* const* d_in, const int* in_sizes, int n_in,
                              void* d_out, int out_size, void* d_ws, size_t ws_size,
                              hipStream_t stream) {
  const float* x    = (const float*)d_in[0];
  const float* wqkv = (const float*)d_in[1];
  const float* ow   = (const float*)d_in[2];
  const float* ob   = (const float*)d_in[3];
  char* ws = (char*)d_ws;
  _Float16* xh    = (_Float16*)(ws);               //  8,388,608 B
  _Float16* wqkvh = (_Float16*)(ws + 8650752);     //  1,572,864 B
  _Float16* owh   = (_Float16*)(ws + 10485760);    //    524,288 B
  _Float16* qbuf  = (_Float16*)(ws + 11534336);    //  8,388,608 B
  _Float16* kbuf  = (_Float16*)(ws + 20971520);    //  8,388,608 B
  _Float16* vTb   = (_Float16*)(ws + 29360128);    //  8,388,608 B
  _Float16* ctxh  = (_Float16*)(ws + 37748736);    //  8,388,608 B
  float2*   rope  = (float2*)  (ws + 46137344);    //    524,288 B -> end 46,661,632

  prep<<<2048, 256, 0, stream>>>(x, wqkv, ow, ws);
  qkv_gemm_mfma<<<dim3(64, 12), 256, 0, stream>>>(xh, wqkvh, rope, qbuf, kbuf, vTb);
  attn_win_mfma<<<dim3(32, 32), 256, 0, stream>>>(qbuf, kbuf, vTb, ctxh);
  out_gemm_mfma<<<dim3(64, 8), 256, 0, stream>>>(ctxh, owh, ob, (float*)d_out);
}